// Round 2
// baseline (2480.700 us; speedup 1.0000x reference)
//
#include <hip/hip_runtime.h>

#define HW_  4096
#define D_   64
#define C_   256
#define ROWS 4
#define NT   256

// One block handles ROWS=4 consecutive i-rows of one batch b.
// Stage 1: scores s[j][r] for all j in [0,4096) -> LDS (fp32, interleaved [j][r]).
// Stage 2: two-pass softmax (block max, exp, block sum).
// Stage 3: PV with wave-sliced channels; epilogue k*sv + x; g passthrough.
__global__ __launch_bounds__(NT, 2) void attn_kernel(
    const float* __restrict__ g,
    const float* __restrict__ x,
    const float* __restrict__ xq,
    const float* __restrict__ pg,
    const float* __restrict__ xv,
    const float* __restrict__ kk,
    float* __restrict__ out)
{
    __shared__ __align__(16) float s_pg[ROWS][D_];
    __shared__ __align__(16) float s_sc[HW_ * ROWS];   // [j][r]
    __shared__ float s_rmax[4][ROWS];
    __shared__ float s_rsum[4][ROWS];

    const int t    = threadIdx.x;
    const int lane = t & 63;
    const int w    = t >> 6;
    const int blk  = blockIdx.x;
    const int b    = blk >> 10;            // HW_/ROWS = 1024 blocks per batch
    const int i0   = (blk & 1023) * ROWS;

    const size_t rowbase = (size_t)b * HW_ + i0;

    // ---- g passthrough (independent of everything else; issue first) ----
    {
        const int r  = t >> 6;
        const int cc = (t & 63) * 4;
        const float4 gv = *(const float4*)(g + (rowbase + r) * C_ + cc);
        *(float4*)(out + (rowbase + r) * (2 * C_) + C_ + cc) = gv;
    }

    // ---- load pg rows into LDS ----
    {
        const int r = t >> 6;
        const int d = t & 63;
        s_pg[r][d] = pg[(rowbase + r) * D_ + d];
    }
    __syncthreads();

    // ---- stage 1: scores ----
    const float* qb = xq + (size_t)b * HW_ * D_;
    float lmax[ROWS];
#pragma unroll
    for (int r = 0; r < ROWS; ++r) lmax[r] = -1e30f;

    for (int jj = 0; jj < HW_ / NT; ++jj) {
        const int j = t + jj * NT;
        const float4* q4p = (const float4*)(qb + (size_t)j * D_);
        float s[ROWS];
#pragma unroll
        for (int r = 0; r < ROWS; ++r) s[r] = 0.f;

#pragma unroll
        for (int u = 0; u < D_ / 8; ++u) {
            const float4 qa = q4p[u * 2];
            const float4 qc = q4p[u * 2 + 1];
#pragma unroll
            for (int r = 0; r < ROWS; ++r) {
                const float4 pa = *(const float4*)&s_pg[r][u * 8];
                const float4 pb = *(const float4*)&s_pg[r][u * 8 + 4];
                s[r] += qa.x * pa.x + qa.y * pa.y + qa.z * pa.z + qa.w * pa.w
                      + qc.x * pb.x + qc.y * pb.y + qc.z * pb.z + qc.w * pb.w;
            }
        }
        float4 s4 = make_float4(s[0], s[1], s[2], s[3]);
        *(float4*)&s_sc[j * ROWS] = s4;
#pragma unroll
        for (int r = 0; r < ROWS; ++r) lmax[r] = fmaxf(lmax[r], s[r]);
    }

    // ---- block max per row ----
#pragma unroll
    for (int r = 0; r < ROWS; ++r) {
        float m = lmax[r];
        for (int o = 32; o > 0; o >>= 1) m = fmaxf(m, __shfl_down(m, o));
        if (lane == 0) s_rmax[w][r] = m;
    }
    __syncthreads();
    float bmax[ROWS];
#pragma unroll
    for (int r = 0; r < ROWS; ++r)
        bmax[r] = fmaxf(fmaxf(s_rmax[0][r], s_rmax[1][r]),
                        fmaxf(s_rmax[2][r], s_rmax[3][r]));

    // ---- exp pass + block sum ----
    float lsum[ROWS];
#pragma unroll
    for (int r = 0; r < ROWS; ++r) lsum[r] = 0.f;

    for (int jj = 0; jj < HW_ / NT; ++jj) {
        const int j = t + jj * NT;
        float4 s4 = *(const float4*)&s_sc[j * ROWS];
        s4.x = __expf(s4.x - bmax[0]);
        s4.y = __expf(s4.y - bmax[1]);
        s4.z = __expf(s4.z - bmax[2]);
        s4.w = __expf(s4.w - bmax[3]);
        *(float4*)&s_sc[j * ROWS] = s4;
        lsum[0] += s4.x; lsum[1] += s4.y; lsum[2] += s4.z; lsum[3] += s4.w;
    }
#pragma unroll
    for (int r = 0; r < ROWS; ++r) {
        float sm = lsum[r];
        for (int o = 32; o > 0; o >>= 1) sm += __shfl_down(sm, o);
        if (lane == 0) s_rsum[w][r] = sm;
    }
    __syncthreads();   // also guarantees all exp writes to s_sc are visible
    float rinv[ROWS];
#pragma unroll
    for (int r = 0; r < ROWS; ++r)
        rinv[r] = 1.f / (s_rsum[0][r] + s_rsum[1][r] + s_rsum[2][r] + s_rsum[3][r]);

    // ---- stage 3: PV ----
    // wave w owns channels [w*64, w*64+64); within a wave, lane group jg=lane>>4
    // handles j === jg (mod 4); 4 channels per lane.
    const int jg = lane >> 4;
    const int c0 = (w * 16 + (lane & 15)) * 4;
    const float* vb = xv + (size_t)b * HW_ * C_;

    float acc[ROWS][4];
#pragma unroll
    for (int r = 0; r < ROWS; ++r)
#pragma unroll
        for (int q = 0; q < 4; ++q) acc[r][q] = 0.f;

#pragma unroll 4
    for (int jj = 0; jj < HW_ / 4; ++jj) {
        const int j = jj * 4 + jg;
        const float4 p4 = *(const float4*)&s_sc[j * ROWS];        // rows 0..3 at col j
        const float4 v4 = *(const float4*)(vb + (size_t)j * C_ + c0);
        acc[0][0] += p4.x * v4.x; acc[0][1] += p4.x * v4.y; acc[0][2] += p4.x * v4.z; acc[0][3] += p4.x * v4.w;
        acc[1][0] += p4.y * v4.x; acc[1][1] += p4.y * v4.y; acc[1][2] += p4.y * v4.z; acc[1][3] += p4.y * v4.w;
        acc[2][0] += p4.z * v4.x; acc[2][1] += p4.z * v4.y; acc[2][2] += p4.z * v4.z; acc[2][3] += p4.z * v4.w;
        acc[3][0] += p4.w * v4.x; acc[3][1] += p4.w * v4.y; acc[3][2] += p4.w * v4.z; acc[3][3] += p4.w * v4.w;
    }

    // reduce across the 4 j-groups (lanes differing in bits 4,5)
#pragma unroll
    for (int r = 0; r < ROWS; ++r)
#pragma unroll
        for (int q = 0; q < 4; ++q) {
            acc[r][q] += __shfl_xor(acc[r][q], 16);
            acc[r][q] += __shfl_xor(acc[r][q], 32);
        }

    // ---- epilogue: out[.., 0:256] = k*sv + x ----
    const float kval = kk[0];
    if (lane < 16) {
        const int c = (w * 16 + lane) * 4;
#pragma unroll
        for (int r = 0; r < ROWS; ++r) {
            const float4 xv4 = *(const float4*)(x + (rowbase + r) * C_ + c);
            float4 ov;
            ov.x = kval * (acc[r][0] * rinv[r]) + xv4.x;
            ov.y = kval * (acc[r][1] * rinv[r]) + xv4.y;
            ov.z = kval * (acc[r][2] * rinv[r]) + xv4.z;
            ov.w = kval * (acc[r][3] * rinv[r]) + xv4.w;
            *(float4*)(out + (rowbase + r) * (2 * C_) + c) = ov;
        }
    }
}

extern "C" void kernel_launch(void* const* d_in, const int* in_sizes, int n_in,
                              void* d_out, int out_size, void* d_ws, size_t ws_size,
                              hipStream_t stream) {
    const float* g  = (const float*)d_in[0];
    const float* x  = (const float*)d_in[1];
    const float* xq = (const float*)d_in[2];
    const float* pg = (const float*)d_in[3];
    const float* xv = (const float*)d_in[4];
    const float* kk = (const float*)d_in[5];
    float* out = (float*)d_out;

    const int B = in_sizes[0] / (HW_ * C_);      // 4
    dim3 grid(B * (HW_ / ROWS));                 // 4096 blocks
    attn_kernel<<<grid, NT, 0, stream>>>(g, x, xq, pg, xv, kk, out);
}

// Round 3
// 254.538 us; speedup vs baseline: 9.7459x; 9.7459x over previous
//
#include <hip/hip_runtime.h>

#define N_  4096
#define D_  64
#define C_  256
#define NT  256

typedef short bf16x8 __attribute__((ext_vector_type(8)));
typedef float f32x4  __attribute__((ext_vector_type(4)));

__device__ __forceinline__ unsigned short f2bf(float f) {
    union { float f; unsigned int i; } v; v.f = f;
    unsigned int r = v.i + 0x7fffu + ((v.i >> 16) & 1u);
    return (unsigned short)(r >> 16);
}

// ---------- prepass 1: fp32 -> bf16 elementwise ----------
__global__ void cvt_kernel(const float* __restrict__ src,
                           unsigned short* __restrict__ dst, int n4) {
    int i = blockIdx.x * blockDim.x + threadIdx.x;
    if (i < n4) {
        float4 v = ((const float4*)src)[i];
        ushort4 o;
        o.x = f2bf(v.x); o.y = f2bf(v.y); o.z = f2bf(v.z); o.w = f2bf(v.w);
        ((ushort4*)dst)[i] = o;
    }
}

// ---------- prepass 2: v[b][j][c] fp32 -> vt[b][c][j] bf16 ----------
__global__ void transpose_kernel(const float* __restrict__ v,
                                 unsigned short* __restrict__ vt) {
    __shared__ float s[64][65];
    const int t  = threadIdx.x;
    const int j0 = blockIdx.x * 64;
    const int c0 = blockIdx.y * 64;
    const int b  = blockIdx.z;
#pragma unroll
    for (int it = 0; it < 16; ++it) {
        const int jl = it * 4 + (t >> 6);
        const int cl = t & 63;
        s[jl][cl] = v[((size_t)b * N_ + j0 + jl) * C_ + c0 + cl];
    }
    __syncthreads();
#pragma unroll
    for (int it = 0; it < 16; ++it) {
        const int cl = it * 4 + (t >> 6);
        const int jl = t & 63;
        vt[((size_t)b * C_ + c0 + cl) * N_ + j0 + jl] = f2bf(s[jl][cl]);
    }
}

// ---------- main: MFMA flash attention (no-max softmax) ----------
// Block: 4 waves, M=32 query rows, loop j in tiles of 64.
// Wave w: S-strip columns [w*16,w*16+16), PV channels [w*64,w*64+64).
__global__ __launch_bounds__(NT, 2) void attn_mfma(
    const float* __restrict__ g,  const float* __restrict__ x,
    const float* __restrict__ kk, float* __restrict__ out,
    const unsigned short* __restrict__ qbf,
    const unsigned short* __restrict__ pgbf,
    const unsigned short* __restrict__ vt)
{
    __shared__ __align__(16) unsigned short p_lds[2][32][72];  // row stride 144B: 16B-aligned, quad bank-shift 16
    __shared__ float l_part[4][32];

    const int t    = threadIdx.x;
    const int lane = t & 63;
    const int w    = t >> 6;
    const int l15  = lane & 15;
    const int quad = lane >> 4;
    const int blk  = blockIdx.x;
    const int b    = blk >> 7;              // N/32 = 128 blocks per batch
    const int i0   = (blk & 127) * 32;
    const size_t rowbase = (size_t)b * N_ + i0;
    const int wc0  = w * 64;

    // ---- g passthrough: out[.., 256:512] = g ----
#pragma unroll
    for (int rr = 0; rr < 8; ++rr) {
        const int row = rr * 4 + w;
        const int c4  = (t & 63) * 4;
        const float4 gv = *(const float4*)(g + (rowbase + row) * C_ + c4);
        *(float4*)(out + (rowbase + row) * (2 * C_) + C_ + c4) = gv;
    }

    // ---- preload pg A-frags (reused for all j-tiles) ----
    bf16x8 pga[2][2];
#pragma unroll
    for (int mt = 0; mt < 2; ++mt)
#pragma unroll
        for (int ks = 0; ks < 2; ++ks)
            pga[mt][ks] = *(const bf16x8*)(pgbf +
                ((size_t)b * N_ + i0 + mt * 16 + l15) * D_ + ks * 32 + quad * 8);

    f32x4 oacc[2][4];
    float ls[2][4];
#pragma unroll
    for (int mt = 0; mt < 2; ++mt)
#pragma unroll
        for (int ct = 0; ct < 4; ++ct) oacc[mt][ct] = (f32x4){0.f, 0.f, 0.f, 0.f};
#pragma unroll
    for (int mt = 0; mt < 2; ++mt)
#pragma unroll
        for (int r = 0; r < 4; ++r) ls[mt][r] = 0.f;

    const unsigned short* qb  = qbf + (size_t)b * N_ * D_;
    const unsigned short* vtb = vt  + (size_t)b * C_ * N_;

    for (int jt = 0; jt < N_ / 64; ++jt) {
        const int j0  = jt * 64;
        const int buf = jt & 1;

        // prefetch V B-frags for this tile (consumed after the barrier)
        bf16x8 vf[2][4];
#pragma unroll
        for (int ks = 0; ks < 2; ++ks)
#pragma unroll
            for (int ct = 0; ct < 4; ++ct)
                vf[ks][ct] = *(const bf16x8*)(vtb +
                    (size_t)(wc0 + ct * 16 + l15) * N_ + j0 + ks * 32 + quad * 8);

        // ---- S = pg . q^T for this wave's 16-column strip ----
        f32x4 sacc[2];
        sacc[0] = (f32x4){0.f, 0.f, 0.f, 0.f};
        sacc[1] = (f32x4){0.f, 0.f, 0.f, 0.f};
#pragma unroll
        for (int ks = 0; ks < 2; ++ks) {
            const bf16x8 qf = *(const bf16x8*)(qb +
                (size_t)(j0 + w * 16 + l15) * D_ + ks * 32 + quad * 8);
            sacc[0] = __builtin_amdgcn_mfma_f32_16x16x32_bf16(pga[0][ks], qf, sacc[0], 0, 0, 0);
            sacc[1] = __builtin_amdgcn_mfma_f32_16x16x32_bf16(pga[1][ks], qf, sacc[1], 0, 0, 0);
        }

        // ---- exp (no max-sub: |s| small enough for fp32), row-sum, P -> LDS ----
#pragma unroll
        for (int mt = 0; mt < 2; ++mt)
#pragma unroll
            for (int r = 0; r < 4; ++r) {
                const float p = __expf(sacc[mt][r]);
                ls[mt][r] += p;
                p_lds[buf][mt * 16 + quad * 4 + r][w * 16 + l15] = f2bf(p);
            }
        __syncthreads();

        // ---- O += P . V (A = P from LDS, B = V^T 16B frags) ----
#pragma unroll
        for (int ks = 0; ks < 2; ++ks) {
            const bf16x8 pa0 = *(const bf16x8*)&p_lds[buf][l15][ks * 32 + quad * 8];
            const bf16x8 pa1 = *(const bf16x8*)&p_lds[buf][16 + l15][ks * 32 + quad * 8];
#pragma unroll
            for (int ct = 0; ct < 4; ++ct) {
                oacc[0][ct] = __builtin_amdgcn_mfma_f32_16x16x32_bf16(pa0, vf[ks][ct], oacc[0][ct], 0, 0, 0);
                oacc[1][ct] = __builtin_amdgcn_mfma_f32_16x16x32_bf16(pa1, vf[ks][ct], oacc[1][ct], 0, 0, 0);
            }
        }
    }

    // ---- row sums: reduce across 16 lanes of quad, then across 4 waves ----
#pragma unroll
    for (int mt = 0; mt < 2; ++mt)
#pragma unroll
        for (int r = 0; r < 4; ++r) {
            float s = ls[mt][r];
            s += __shfl_xor(s, 1); s += __shfl_xor(s, 2);
            s += __shfl_xor(s, 4); s += __shfl_xor(s, 8);
            ls[mt][r] = s;
        }
    if (l15 == 0) {
#pragma unroll
        for (int mt = 0; mt < 2; ++mt)
#pragma unroll
            for (int r = 0; r < 4; ++r)
                l_part[w][mt * 16 + quad * 4 + r] = ls[mt][r];
    }
    __syncthreads();

    // ---- epilogue: out[.., 0:256] = k * O / l + x ----
    const float kval = kk[0];
#pragma unroll
    for (int mt = 0; mt < 2; ++mt)
#pragma unroll
        for (int r = 0; r < 4; ++r) {
            const int m = mt * 16 + quad * 4 + r;
            const float linv = 1.f / (l_part[0][m] + l_part[1][m] + l_part[2][m] + l_part[3][m]);
            const size_t row = rowbase + m;
#pragma unroll
            for (int ct = 0; ct < 4; ++ct) {
                const int c = wc0 + ct * 16 + l15;
                out[row * (2 * C_) + c] = kval * (oacc[mt][ct][r] * linv) + x[row * C_ + c];
            }
        }
}

// ---------- fallback (round-2 kernel) if workspace too small ----------
#define ROWS 4
__global__ __launch_bounds__(NT, 2) void attn_fallback(
    const float* __restrict__ g, const float* __restrict__ x,
    const float* __restrict__ xq, const float* __restrict__ pg,
    const float* __restrict__ xv, const float* __restrict__ kk,
    float* __restrict__ out)
{
    __shared__ __align__(16) float s_pg[ROWS][D_];
    __shared__ __align__(16) float s_sc[N_ * ROWS];
    __shared__ float s_rmax[4][ROWS];
    __shared__ float s_rsum[4][ROWS];

    const int t = threadIdx.x, lane = t & 63, w = t >> 6, blk = blockIdx.x;
    const int b = blk >> 10, i0 = (blk & 1023) * ROWS;
    const size_t rowbase = (size_t)b * N_ + i0;
    {
        const int r = t >> 6, cc = (t & 63) * 4;
        const float4 gv = *(const float4*)(g + (rowbase + r) * C_ + cc);
        *(float4*)(out + (rowbase + r) * (2 * C_) + C_ + cc) = gv;
    }
    { const int r = t >> 6, d = t & 63; s_pg[r][d] = pg[(rowbase + r) * D_ + d]; }
    __syncthreads();
    const float* qb = xq + (size_t)b * N_ * D_;
    float lmax[ROWS];
#pragma unroll
    for (int r = 0; r < ROWS; ++r) lmax[r] = -1e30f;
    for (int jj = 0; jj < N_ / NT; ++jj) {
        const int j = t + jj * NT;
        const float4* q4p = (const float4*)(qb + (size_t)j * D_);
        float s[ROWS] = {0.f, 0.f, 0.f, 0.f};
#pragma unroll
        for (int u = 0; u < D_ / 8; ++u) {
            const float4 qa = q4p[u * 2], qc = q4p[u * 2 + 1];
#pragma unroll
            for (int r = 0; r < ROWS; ++r) {
                const float4 pa = *(const float4*)&s_pg[r][u * 8];
                const float4 pb = *(const float4*)&s_pg[r][u * 8 + 4];
                s[r] += qa.x * pa.x + qa.y * pa.y + qa.z * pa.z + qa.w * pa.w
                      + qc.x * pb.x + qc.y * pb.y + qc.z * pb.z + qc.w * pb.w;
            }
        }
        *(float4*)&s_sc[j * ROWS] = make_float4(s[0], s[1], s[2], s[3]);
#pragma unroll
        for (int r = 0; r < ROWS; ++r) lmax[r] = fmaxf(lmax[r], s[r]);
    }
#pragma unroll
    for (int r = 0; r < ROWS; ++r) {
        float m = lmax[r];
        for (int o = 32; o > 0; o >>= 1) m = fmaxf(m, __shfl_down(m, o));
        if (lane == 0) s_rmax[w][r] = m;
    }
    __syncthreads();
    float bmax[ROWS];
#pragma unroll
    for (int r = 0; r < ROWS; ++r)
        bmax[r] = fmaxf(fmaxf(s_rmax[0][r], s_rmax[1][r]), fmaxf(s_rmax[2][r], s_rmax[3][r]));
    float lsum[ROWS] = {0.f, 0.f, 0.f, 0.f};
    for (int jj = 0; jj < N_ / NT; ++jj) {
        const int j = t + jj * NT;
        float4 s4 = *(const float4*)&s_sc[j * ROWS];
        s4.x = __expf(s4.x - bmax[0]); s4.y = __expf(s4.y - bmax[1]);
        s4.z = __expf(s4.z - bmax[2]); s4.w = __expf(s4.w - bmax[3]);
        *(float4*)&s_sc[j * ROWS] = s4;
        lsum[0] += s4.x; lsum[1] += s4.y; lsum[2] += s4.z; lsum[3] += s4.w;
    }
#pragma unroll
    for (int r = 0; r < ROWS; ++r) {
        float sm = lsum[r];
        for (int o = 32; o > 0; o >>= 1) sm += __shfl_down(sm, o);
        if (lane == 0) s_rsum[w][r] = sm;
    }
    __syncthreads();
    float rinv[ROWS];
#pragma unroll
    for (int r = 0; r < ROWS; ++r)
        rinv[r] = 1.f / (s_rsum[0][r] + s_rsum[1][r] + s_rsum[2][r] + s_rsum[3][r]);
    const int jg = lane >> 4;
    const int c0 = (w * 16 + (lane & 15)) * 4;
    const float* vb = xv + (size_t)b * N_ * C_;
    float acc[ROWS][4];
#pragma unroll
    for (int r = 0; r < ROWS; ++r)
#pragma unroll
        for (int q = 0; q < 4; ++q) acc[r][q] = 0.f;
#pragma unroll 4
    for (int jj = 0; jj < N_ / 4; ++jj) {
        const int j = jj * 4 + jg;
        const float4 p4 = *(const float4*)&s_sc[j * ROWS];
        const float4 v4 = *(const float4*)(vb + (size_t)j * C_ + c0);
        acc[0][0] += p4.x * v4.x; acc[0][1] += p4.x * v4.y; acc[0][2] += p4.x * v4.z; acc[0][3] += p4.x * v4.w;
        acc[1][0] += p4.y * v4.x; acc[1][1] += p4.y * v4.y; acc[1][2] += p4.y * v4.z; acc[1][3] += p4.y * v4.w;
        acc[2][0] += p4.z * v4.x; acc[2][1] += p4.z * v4.y; acc[2][2] += p4.z * v4.z; acc[2][3] += p4.z * v4.w;
        acc[3][0] += p4.w * v4.x; acc[3][1] += p4.w * v4.y; acc[3][2] += p4.w * v4.z; acc[3][3] += p4.w * v4.w;
    }
#pragma unroll
    for (int r = 0; r < ROWS; ++r)
#pragma unroll
        for (int q = 0; q < 4; ++q) {
            acc[r][q] += __shfl_xor(acc[r][q], 16);
            acc[r][q] += __shfl_xor(acc[r][q], 32);
        }
    const float kval = kk[0];
    if (lane < 16) {
        const int c = (w * 16 + lane) * 4;
#pragma unroll
        for (int r = 0; r < ROWS; ++r) {
            const float4 xv4 = *(const float4*)(x + (rowbase + r) * C_ + c);
            float4 ov;
            ov.x = kval * (acc[r][0] * rinv[r]) + xv4.x;
            ov.y = kval * (acc[r][1] * rinv[r]) + xv4.y;
            ov.z = kval * (acc[r][2] * rinv[r]) + xv4.z;
            ov.w = kval * (acc[r][3] * rinv[r]) + xv4.w;
            *(float4*)(out + (rowbase + r) * (2 * C_) + c) = ov;
        }
    }
}

extern "C" void kernel_launch(void* const* d_in, const int* in_sizes, int n_in,
                              void* d_out, int out_size, void* d_ws, size_t ws_size,
                              hipStream_t stream) {
    const float* g  = (const float*)d_in[0];
    const float* x  = (const float*)d_in[1];
    const float* xq = (const float*)d_in[2];
    const float* pg = (const float*)d_in[3];
    const float* xv = (const float*)d_in[4];
    const float* kk = (const float*)d_in[5];
    float* out = (float*)d_out;

    const int B = in_sizes[0] / (N_ * C_);   // 4
    const size_t qn = (size_t)B * N_ * D_;   // elements of q / pg
    const size_t vn = (size_t)B * N_ * C_;   // elements of v
    const size_t need = (2 * qn + vn) * sizeof(unsigned short);

    if (ws_size < need) {
        attn_fallback<<<dim3(B * (N_ / ROWS)), NT, 0, stream>>>(g, x, xq, pg, xv, kk, out);
        return;
    }

    unsigned short* qbf  = (unsigned short*)d_ws;
    unsigned short* pgbf = qbf + qn;
    unsigned short* vtw  = pgbf + qn;

    const int n4 = (int)(qn / 4);
    cvt_kernel<<<dim3((n4 + 255) / 256), 256, 0, stream>>>(xq, qbf, n4);
    cvt_kernel<<<dim3((n4 + 255) / 256), 256, 0, stream>>>(pg, pgbf, n4);
    transpose_kernel<<<dim3(N_ / 64, C_ / 64, B), 256, 0, stream>>>(xv, vtw);

    attn_mfma<<<dim3(B * (N_ / 32)), NT, 0, stream>>>(g, x, kk, out, qbf, pgbf, vtw);
}